// Round 12
// baseline (226.518 us; speedup 1.0000x reference)
//
#include <hip/hip_runtime.h>

typedef unsigned short u16;
typedef unsigned int   u32;
typedef unsigned long long u64;
typedef __bf16 bf16;
typedef float f32x4  __attribute__((ext_vector_type(4)));
typedef bf16  bf16x8 __attribute__((ext_vector_type(8)));

__device__ __forceinline__ float bf2f(u16 u){ return (float)__builtin_bit_cast(bf16,u); }
__device__ __forceinline__ u16   f2bf(float f){ return __builtin_bit_cast(u16,(bf16)f); }
__device__ __forceinline__ u32   pkbf(float a,float b){ return (u32)f2bf(a)|((u32)f2bf(b)<<16); }

#define NROWS 32768

// ---- basis: 8 bf16 slots, NO c6 (folded into B); d2(u)=d1(1-u), d0=w1^3, d3=u^3 ----
__device__ __forceinline__ uint4 basis_pk(float x)
{
  float tp  = __fmaf_rn(x, 2.5f, 5.5f);
  float tpc = fminf(fmaxf(tp, -1.0f), 12.0f);   // out-of-range -> window miss -> zeros
  float fi  = floorf(tpc);
  float uu  = tpc - fi;
  int   i0  = (int)fi;
  float u2 = uu*uu, u3 = u2*uu, w1 = 1.0f-uu, w2 = w1*w1, w3 = w2*w1;
  float d1 = __fmaf_rn(3.0f, u3, __fmaf_rn(-6.0f, u2, 4.0f));
  float d2 = __fmaf_rn(3.0f, w3, __fmaf_rn(-6.0f, w2, 4.0f));
  u64 dpk = (u64)pkbf(w3, d1) | ((u64)pkbf(d2, u3) << 32);
  int ss = i0*16 - 48;
  u64 A  = dpk << (ss & 63);
  u64 Bv = dpk >> ((64-ss) & 63);
  u64 Cv = dpk << ((ss-64) & 63);
  u64 Dv = dpk >> ((-ss) & 63);
  u64 lo = (ss>=0 && ss<64)   ? A  : ((ss<0 && ss>-64) ? Dv : 0ull);
  u64 hi = (ss>=64 && ss<128) ? Cv : ((ss>0 && ss<64)  ? Bv : 0ull);
  uint4 r; r.x=(u32)lo; r.y=(u32)(lo>>32); r.z=(u32)hi; r.w=(u32)(hi>>32);
  return r;
}

// main-layer expansion: single silu slot + bases
__device__ __forceinline__ void expand9(float x, u16& sil, uint4& bpk)
{
  float s = x * (1.0f/(1.0f+__expf(-x)));
  sil = f2bf(s);
  bpk = basis_pk(x);
}
// tail expansion: silu hi/lo pair + bases
__device__ __forceinline__ void expand10(float x, u32& spk, uint4& bpk)
{
  float s = x * (1.0f/(1.0f+__expf(-x)));
  u16 uh = f2bf(s);
  u16 ul = f2bf(s - bf2f(uh));
  spk = (u32)uh | ((u32)ul<<16);
  bpk = basis_pk(x);
}

// ---------------- destination-major weight prep, two formats ----------------
struct PrepArgs {
  const float* bw[7]; const float* sw[7]; const float* sc[7];
  u16* w[7];
  int cin[7]; int coutr[7]; int ntsh[7]; int fmt[7];
  u32 elems[7];
};

__global__ __launch_bounds__(256) void prep_kernel(PrepArgs pa)
{
  u32 idx = blockIdx.x*256 + threadIdx.x;
  int L = 0;
  u32 off = idx;
  while (L < 6 && off >= pa.elems[L]) { off -= pa.elems[L]; ++L; }
  int j    = off & 7;
  int lane = (off>>3) & 63;
  u32 tl   = off >> 9;
  int ntsh = pa.ntsh[L];
  u32 kstep = tl >> ntsh;
  int ntile = (int)(tl & ((1u<<ntsh)-1u));
  int o    = ntile*16 + (lane&15);
  int kpos = (lane>>4)*8 + j;
  int i = 0, g = 0; bool sil;
  if (pa.fmt[L] == 0){
    u32 c = kstep/9u; int r = (int)(kstep - c*9u);
    if (r == 0){ i = (int)c*32 + kpos; sil = true; }
    else { int kl=(r-1)*32+kpos; i=(int)c*32+(kl>>3); g=kl&7; sil = false; }
  } else {
    u32 c = kstep/5u; int r = (int)(kstep - c*5u);
    if (r == 0){ i = (int)c*16 + (kpos>>1); sil = true; }
    else { int kl=(r-1)*32+kpos; i=(int)c*16+(kl>>3); g=kl&7; sil = false; }
  }
  float v = 0.f;
  if (o < pa.coutr[L]) {
    size_t e = (size_t)o*pa.cin[L] + i;
    v = sil ? pa.bw[L][e] : pa.sw[L][e*8+g]*pa.sc[L][e]*0.16666666666666666f;
  }
  pa.w[L][off] = f2bf(v);
}

// ---------------- kan phase (device fn): 64-row slab, 8 waves 1x8 grid ----------------
// Proven r10 structure: double-buffered chunks, modular bbuf slots, ptr-increment W.
template<int CIN,int COUT,int IN_MODE,int OUT_MODE>
__device__ __forceinline__ void kan_phase(u32* smem, int b0, int tid,
    const void* hin_, const u16* __restrict__ W, void* hout_)
{
  constexpr int NCH = CIN/32;
  constexpr int TOTK = NCH*9;
  constexpr int NTILES = COUT/16;
  constexpr int NTL = NTILES/8;
  constexpr int SROW=20, BROW=132, BOFF=64*SROW;
  constexpr int CHUNK = BOFF + 64*BROW;          // 9728 dw
  constexpr int WSTEP = NTILES*512;

  const int wave = tid>>6, lane = tid&63, m = lane&15, quad = lane>>4;
  const int cg = wave;

  const u16*   hb = (const u16*)hin_;
  const float* hf = (const float*)hin_;

  f32x4 acc[4][NTL];
#pragma unroll
  for (int a=0;a<4;++a)
#pragma unroll
    for (int n=0;n<NTL;++n) acc[a][n]=(f32x4){0.f,0.f,0.f,0.f};

  const u16* wq = W + ((size_t)(cg*NTL)*64 + lane)*8;
  bf16x8 bbuf[3][NTL];
  auto loadB = [&](int kstep, bf16x8* dst){
    if (kstep < TOTK){
#pragma unroll
      for (int nt=0; nt<NTL; ++nt)
        dst[nt] = *(const bf16x8*)(wq + nt*512);
    }
    wq += WSTEP;
  };
  loadB(0, bbuf[0]); loadB(1, bbuf[1]);

  float xb[2][4];
  auto loadX = [&](int kc, float* dst){
#pragma unroll
    for (int t=0;t<4;++t){
      int task = t*512+tid, row = task>>5, f = task&31;
      int gi = (b0+row)*CIN + kc*32 + f;
      dst[t] = (IN_MODE==0)? hf[gi] : bf2f(hb[gi]);
    }
  };
  auto expandChunk = [&](const float* xc, u32* dstb){
#pragma unroll
    for (int t=0;t<4;++t){
      int task=t*512+tid, row=task>>5, f=task&31;
      u16 sil; uint4 bpk;
      expand9(xc[t], sil, bpk);
      ((u16*)dstb)[row*(SROW*2) + f] = sil;
      *(uint4*)&dstb[BOFF + row*BROW + f*4] = bpk;
    }
  };

  loadX(0, xb[0]);
  expandChunk(xb[0], smem);
  if (NCH > 1) loadX(1, xb[1]);
  __syncthreads();

  for (int kc=0; kc<NCH; ++kc){
    u32* cur = smem + (kc&1)*CHUNK;
    u32* nxt = smem + ((kc+1)&1)*CHUNK;
    if (kc+1 < NCH) expandChunk(xb[(kc+1)&1], nxt);
    if (kc+2 < NCH) loadX(kc+2, xb[kc&1]);
#pragma unroll
    for (int ks=0; ks<9; ++ks){
      loadB(kc*9+ks+2, bbuf[(ks+2)%3]);          // compile-time slot (ks unrolled, 9%3==0)
      bf16x8 af[4];
#pragma unroll
      for (int mt=0; mt<4; ++mt){
        int row = mt*16 + m;
        af[mt] = (ks==0)
          ? *(const bf16x8*)&cur[row*SROW + quad*4]
          : *(const bf16x8*)&cur[BOFF + row*BROW + (ks-1)*16 + quad*4];
      }
#pragma unroll
      for (int nt=0; nt<NTL; ++nt)
#pragma unroll
        for (int mt=0; mt<4; ++mt)
          acc[mt][nt] = __builtin_amdgcn_mfma_f32_16x16x32_bf16(af[mt], bbuf[ks%3][nt], acc[mt][nt],0,0,0);
    }
    __syncthreads();
  }

#pragma unroll
  for (int mt=0; mt<4; ++mt)
#pragma unroll
    for (int nt=0; nt<NTL; ++nt)
#pragma unroll
      for (int r=0; r<4; ++r){
        size_t off = (size_t)(b0 + mt*16 + quad*4 + r)*COUT + (cg*NTL+nt)*16 + m;
        if constexpr (OUT_MODE==0) ((float*)hout_)[off] = acc[mt][nt][r];
        else                       ((u16*)hout_)[off]   = f2bf(acc[mt][nt][r]);
      }
}

// ---------------- tail body (device fn): h1 -> h2(LDS) -> {L3,L5} -> L4->adv ; L6->val ----
// Verbatim r10 tail2 structure (serial B1/B2 — r11's merged-B regressed).
template<int IN_MODE>
__device__ __forceinline__ void tail_body(u32* smem, int b0, int tid,
  const void* h1_,
  const u16* __restrict__ W2, const u16* __restrict__ W3, const u16* __restrict__ W4,
  const u16* __restrict__ W5, const u16* __restrict__ W6,
  float* __restrict__ out_adv, float* __restrict__ out_val)
{
  float* hH = (float*)smem;               // [64][65]
  float* hA = (float*)(smem + 4160);      // [64][65]
  float* hV = (float*)(smem + 8320);      // [64][65]
  u32*  Aex = smem + 12480;               // 64*20 + 64*68 = 5632 dw

  const int wave = tid>>6, lane = tid&63, m = lane&15, quad = lane>>4;
  const int rg = wave>>2, cg = wave&3;

  const u16*   hb = (const u16*)h1_;
  const float* hf = (const float*)h1_;

  // ======== phase K: L2 ========
  {
    constexpr int CIN=256, NCH=8, TOTK=72, NTILES=4;
    constexpr int SROW=20, BROW=132, BOFF=64*SROW, CHUNK=BOFF+64*BROW; // 9728 dw
    f32x4 acc[2];
    acc[0]=(f32x4){0,0,0,0}; acc[1]=(f32x4){0,0,0,0};
    const u16* wq = W2 + ((size_t)cg*64 + lane)*8;
    bf16x8 bb[3];
    auto loadB = [&](int kstep, bf16x8* dst){
      if (kstep < TOTK) *dst = *(const bf16x8*)wq;
      wq += NTILES*512;
    };
    loadB(0,&bb[0]); loadB(1,&bb[1]);
    float xb[2][4];
    auto loadX = [&](int kc, float* dst){
#pragma unroll
      for (int t=0;t<4;++t){
        int task=t*512+tid, row=task>>5, f=task&31;
        int gi=(b0+row)*CIN + kc*32 + f;
        dst[t] = (IN_MODE==0)? hf[gi] : bf2f(hb[gi]);
      }
    };
    auto expandChunk = [&](const float* xc, u32* dstb){
#pragma unroll
      for (int t=0;t<4;++t){
        int task=t*512+tid, row=task>>5, f=task&31;
        u16 sil; uint4 bpk;
        expand9(xc[t], sil, bpk);
        ((u16*)dstb)[row*(SROW*2)+f] = sil;
        *(uint4*)&dstb[BOFF + row*BROW + f*4] = bpk;
      }
    };
    loadX(0, xb[0]);
    expandChunk(xb[0], smem);
    loadX(1, xb[1]);
    __syncthreads();
    for (int kc=0; kc<NCH; ++kc){
      u32* cur = smem + (kc&1)*CHUNK;
      u32* nxt = smem + ((kc+1)&1)*CHUNK;
      if (kc+1 < NCH) expandChunk(xb[(kc+1)&1], nxt);
      if (kc+2 < NCH) loadX(kc+2, xb[kc&1]);
#pragma unroll
      for (int ks=0; ks<9; ++ks){
        loadB(kc*9+ks+2, &bb[(ks+2)%3]);
        bf16x8 af[2];
#pragma unroll
        for (int mt=0; mt<2; ++mt){
          int row = rg*32 + mt*16 + m;
          af[mt] = (ks==0)
            ? *(const bf16x8*)&cur[row*SROW + quad*4]
            : *(const bf16x8*)&cur[BOFF + row*BROW + (ks-1)*16 + quad*4];
        }
#pragma unroll
        for (int mt=0; mt<2; ++mt)
          acc[mt] = __builtin_amdgcn_mfma_f32_16x16x32_bf16(af[mt], bb[ks%3], acc[mt],0,0,0);
      }
      __syncthreads();
    }
    // h2 tile -> LDS overlay (safe: after final barrier, staging is dead)
#pragma unroll
    for (int mt=0; mt<2; ++mt)
#pragma unroll
      for (int r=0;r<4;++r)
        hH[(rg*32 + mt*16 + quad*4 + r)*65 + cg*16 + m] = acc[mt][r];
  }
  __syncthreads();

  // ======== tail phase A: expand hH once, accumulate L3 & L5 ========
  constexpr int SROW=20, BROW=68, BOFF=64*20;

  f32x4 a3[2], a5[2];
#pragma unroll
  for (int mt=0;mt<2;++mt){ a3[mt]=(f32x4){0,0,0,0}; a5[mt]=(f32x4){0,0,0,0}; }

  const u16* w3q = W3 + ((size_t)cg*64 + lane)*8;
  const u16* w5q = W5 + ((size_t)cg*64 + lane)*8;
  bf16x8 w3b[3], w5b[3];
  auto loadB2 = [&](int kstep, int d){
    if (kstep < 20){
      w3b[d] = *(const bf16x8*)w3q;
      w5b[d] = *(const bf16x8*)w5q;
    }
    w3q += 4*512; w5q += 4*512;
  };
  loadB2(0,0); loadB2(1,1);

  for (int kc=0; kc<4; ++kc){
#pragma unroll
    for (int t=0;t<2;++t){
      int task=t*512+tid, row=task>>4, f=task&15;
      u32 spk; uint4 bpk;
      expand10(hH[row*65 + kc*16 + f], spk, bpk);
      Aex[row*SROW + f] = spk;
      *(uint4*)&Aex[BOFF + row*BROW + f*4] = bpk;
    }
    __syncthreads();
#pragma unroll
    for (int ks=0; ks<5; ++ks){
      loadB2(kc*5+ks+2, 2);
      bf16x8 af[2];
#pragma unroll
      for (int mt=0; mt<2; ++mt){
        int row = rg*32 + mt*16 + m;
        af[mt] = (ks==0)
          ? *(const bf16x8*)&Aex[row*SROW + quad*4]
          : *(const bf16x8*)&Aex[BOFF + row*BROW + (ks-1)*16 + quad*4];
      }
#pragma unroll
      for (int mt=0; mt<2; ++mt){
        a3[mt] = __builtin_amdgcn_mfma_f32_16x16x32_bf16(af[mt], w3b[0], a3[mt],0,0,0);
        a5[mt] = __builtin_amdgcn_mfma_f32_16x16x32_bf16(af[mt], w5b[0], a5[mt],0,0,0);
      }
      w3b[0]=w3b[1]; w3b[1]=w3b[2]; w5b[0]=w5b[1]; w5b[1]=w5b[2];
    }
    __syncthreads();
  }
#pragma unroll
  for (int mt=0;mt<2;++mt)
#pragma unroll
    for (int r=0;r<4;++r){
      int row = rg*32 + mt*16 + quad*4 + r;
      hA[row*65 + cg*16 + m] = a3[mt][r];
      hV[row*65 + cg*16 + m] = a5[mt][r];
    }
  __syncthreads();

  // ---- phase B1: hA -> L4 -> advantage ----
  f32x4 a4[2];
#pragma unroll
  for (int mt=0;mt<2;++mt) a4[mt]=(f32x4){0,0,0,0};
  const u16* w4q = W4 + ((size_t)cg*64 + lane)*8;
  bf16x8 w4b[3];
  auto loadB4 = [&](int kstep, int d){
    if (kstep < 20) w4b[d] = *(const bf16x8*)w4q;
    w4q += 4*512;
  };
  loadB4(0,0); loadB4(1,1);
  for (int kc=0; kc<4; ++kc){
#pragma unroll
    for (int t=0;t<2;++t){
      int task=t*512+tid, row=task>>4, f=task&15;
      u32 spk; uint4 bpk;
      expand10(hA[row*65 + kc*16 + f], spk, bpk);
      Aex[row*SROW + f] = spk;
      *(uint4*)&Aex[BOFF + row*BROW + f*4] = bpk;
    }
    __syncthreads();
#pragma unroll
    for (int ks=0; ks<5; ++ks){
      loadB4(kc*5+ks+2, 2);
      bf16x8 af[2];
#pragma unroll
      for (int mt=0; mt<2; ++mt){
        int row = rg*32 + mt*16 + m;
        af[mt] = (ks==0)
          ? *(const bf16x8*)&Aex[row*SROW + quad*4]
          : *(const bf16x8*)&Aex[BOFF + row*BROW + (ks-1)*16 + quad*4];
      }
#pragma unroll
      for (int mt=0; mt<2; ++mt)
        a4[mt] = __builtin_amdgcn_mfma_f32_16x16x32_bf16(af[mt], w4b[0], a4[mt],0,0,0);
      w4b[0]=w4b[1]; w4b[1]=w4b[2];
    }
    __syncthreads();
  }
  {
    int col = cg*16 + m;
    if (col < 18){
#pragma unroll
      for (int mt=0;mt<2;++mt)
#pragma unroll
        for (int r=0;r<4;++r)
          out_adv[(size_t)(b0 + rg*32 + mt*16 + quad*4 + r)*18 + col] = a4[mt][r];
    }
  }

  // ---- phase B2: hV -> L6 -> value ----
  f32x4 a6[2];
#pragma unroll
  for (int mt=0;mt<2;++mt) a6[mt]=(f32x4){0,0,0,0};
  const u16* w6q = W6 + ((size_t)cg*64 + lane)*8;
  bf16x8 w6b[3];
  auto loadB6 = [&](int kstep, int d){
    if (kstep < 20) w6b[d] = *(const bf16x8*)w6q;
    w6q += 4*512;
  };
  loadB6(0,0); loadB6(1,1);
  for (int kc=0; kc<4; ++kc){
#pragma unroll
    for (int t=0;t<2;++t){
      int task=t*512+tid, row=task>>4, f=task&15;
      u32 spk; uint4 bpk;
      expand10(hV[row*65 + kc*16 + f], spk, bpk);
      Aex[row*SROW + f] = spk;
      *(uint4*)&Aex[BOFF + row*BROW + f*4] = bpk;
    }
    __syncthreads();
#pragma unroll
    for (int ks=0; ks<5; ++ks){
      loadB6(kc*5+ks+2, 2);
      bf16x8 af[2];
#pragma unroll
      for (int mt=0; mt<2; ++mt){
        int row = rg*32 + mt*16 + m;
        af[mt] = (ks==0)
          ? *(const bf16x8*)&Aex[row*SROW + quad*4]
          : *(const bf16x8*)&Aex[BOFF + row*BROW + (ks-1)*16 + quad*4];
      }
#pragma unroll
      for (int mt=0; mt<2; ++mt)
        a6[mt] = __builtin_amdgcn_mfma_f32_16x16x32_bf16(af[mt], w6b[0], a6[mt],0,0,0);
      w6b[0]=w6b[1]; w6b[1]=w6b[2];
    }
    __syncthreads();
  }
  if (cg==0 && m==0){
#pragma unroll
    for (int mt=0;mt<2;++mt)
#pragma unroll
      for (int r=0;r<4;++r)
        out_val[b0 + rg*32 + mt*16 + quad*4 + r] = a6[mt][r];
  }
}

// ---------------- mega kernel: L0 -> L1 -> L2 -> tail, one 64-row slab per block ----
// Block-local dependency chain (layer outputs are row-slab aligned): h0/h1 bounce
// through global but are written and re-read by the SAME block (L1/L2-hot), with
// __syncthreads() providing workgroup-scope visibility. One kernel = no
// inter-layer launch/drain boundaries. All phases share the same 77824-B LDS.
template<int MID>
__global__ __launch_bounds__(512,4) void mega_kernel(
  const float* __restrict__ x, void* h0_, void* h1_,
  const u16* __restrict__ W0, const u16* __restrict__ W1, const u16* __restrict__ W2,
  const u16* __restrict__ W3, const u16* __restrict__ W4,
  const u16* __restrict__ W5, const u16* __restrict__ W6,
  float* __restrict__ out_adv, float* __restrict__ out_val)
{
  __shared__ __align__(16) u32 smem[19456];
  const int b0 = blockIdx.x*64;
  const int tid = threadIdx.x;

  kan_phase<128,256,0,MID>(smem, b0, tid, x, W0, h0_);
  __syncthreads();                                  // h0 stores visible to block
  kan_phase<256,256,MID,MID>(smem, b0, tid, h0_, W1, h1_);
  __syncthreads();                                  // h1 stores visible to block
  tail_body<MID>(smem, b0, tid, h1_, W2, W3, W4, W5, W6, out_adv, out_val);
}

extern "C" void kernel_launch(void* const* d_in, const int* in_sizes, int n_in,
                              void* d_out, int out_size, void* d_ws, size_t ws_size,
                              hipStream_t stream)
{
  (void)in_sizes; (void)n_in; (void)out_size;
  char* ws = (char*)d_ws;

  // W layouts: L0 36 ksteps x16 tiles, L1 72x16, L2 72x4, L3-6 20x4
  const size_t wbytes[7] = {589824u, 1179648u, 294912u, 81920u, 81920u, 81920u, 81920u};
  const bool midf32 = ws_size >= 77889536u;

  u16* W[7];
  char *h0, *h1;
  if (midf32) {
    h0 = ws;                       // 32768x256 f32
    h1 = h0 + 33554432u;
    size_t off = 75497472u;
    for (int l=0;l<7;++l){ W[l] = (u16*)(ws+off); off += wbytes[l]; }
  } else {
    h0 = ws;                       // bf16 fallback
    h1 = h0 + 16777216u;
    size_t off = 37748736u;
    for (int l=0;l<7;++l){ W[l] = (u16*)(ws+off); off += wbytes[l]; }
  }

  PrepArgs pa;
  const int cins[7]   = {128,256,256,64,64,64,64};
  const int coutr[7]  = {256,256,64,64,18,64,1};
  const int ntsh[7]   = {4,4,2,2,2,2,2};
  const int fmts[7]   = {0,0,0,1,1,1,1};
  const u32 elems[7]  = {294912u,589824u,147456u,40960u,40960u,40960u,40960u};
  for (int l=0;l<7;++l){
    pa.bw[l] = (const float*)d_in[1+3*l];
    pa.sw[l] = (const float*)d_in[2+3*l];
    pa.sc[l] = (const float*)d_in[3+3*l];
    pa.w[l]  = W[l];
    pa.cin[l]=cins[l]; pa.coutr[l]=coutr[l]; pa.ntsh[l]=ntsh[l]; pa.fmt[l]=fmts[l];
    pa.elems[l]=elems[l];
  }
  prep_kernel<<<4672, 256, 0, stream>>>(pa);

  dim3 g64(NROWS/64), bl(512);
  float* out_adv = (float*)d_out;
  float* out_val = (float*)d_out + (size_t)NROWS*18;
  if (midf32) {
    mega_kernel<0><<<g64,bl,0,stream>>>((const float*)d_in[0], h0, h1,
      W[0],W[1],W[2],W[3],W[4],W[5],W[6], out_adv, out_val);
  } else {
    mega_kernel<1><<<g64,bl,0,stream>>>((const float*)d_in[0], h0, h1,
      W[0],W[1],W[2],W[3],W[4],W[5],W[6], out_adv, out_val);
  }
}

// Round 14
// 220.853 us; speedup vs baseline: 1.0257x; 1.0257x over previous
//
#include <hip/hip_runtime.h>

typedef unsigned short u16;
typedef unsigned int   u32;
typedef unsigned long long u64;
typedef __bf16 bf16;
typedef float f32x4  __attribute__((ext_vector_type(4)));
typedef bf16  bf16x8 __attribute__((ext_vector_type(8)));

__device__ __forceinline__ float bf2f(u16 u){ return (float)__builtin_bit_cast(bf16,u); }
__device__ __forceinline__ u16   f2bf(float f){ return __builtin_bit_cast(u16,(bf16)f); }
__device__ __forceinline__ u32   pkbf(float a,float b){ return (u32)f2bf(a)|((u32)f2bf(b)<<16); }

#define NROWS 32768

// ---- basis: 8 bf16 slots, NO c6 (folded into B); d2(u)=d1(1-u), d0=w1^3, d3=u^3 ----
__device__ __forceinline__ uint4 basis_pk(float x)
{
  float tp  = __fmaf_rn(x, 2.5f, 5.5f);
  float tpc = fminf(fmaxf(tp, -1.0f), 12.0f);   // out-of-range -> window miss -> zeros
  float fi  = floorf(tpc);
  float uu  = tpc - fi;
  int   i0  = (int)fi;
  float u2 = uu*uu, u3 = u2*uu, w1 = 1.0f-uu, w2 = w1*w1, w3 = w2*w1;
  float d1 = __fmaf_rn(3.0f, u3, __fmaf_rn(-6.0f, u2, 4.0f));
  float d2 = __fmaf_rn(3.0f, w3, __fmaf_rn(-6.0f, w2, 4.0f));
  u64 dpk = (u64)pkbf(w3, d1) | ((u64)pkbf(d2, u3) << 32);
  int ss = i0*16 - 48;
  u64 A  = dpk << (ss & 63);
  u64 Bv = dpk >> ((64-ss) & 63);
  u64 Cv = dpk << ((ss-64) & 63);
  u64 Dv = dpk >> ((-ss) & 63);
  u64 lo = (ss>=0 && ss<64)   ? A  : ((ss<0 && ss>-64) ? Dv : 0ull);
  u64 hi = (ss>=64 && ss<128) ? Cv : ((ss>0 && ss<64)  ? Bv : 0ull);
  uint4 r; r.x=(u32)lo; r.y=(u32)(lo>>32); r.z=(u32)hi; r.w=(u32)(hi>>32);
  return r;
}

// main-layer expansion: single silu slot + bases
__device__ __forceinline__ void expand9(float x, u16& sil, uint4& bpk)
{
  float s = x * (1.0f/(1.0f+__expf(-x)));
  sil = f2bf(s);
  bpk = basis_pk(x);
}
// tail expansion: silu hi/lo pair + bases
__device__ __forceinline__ void expand10(float x, u32& spk, uint4& bpk)
{
  float s = x * (1.0f/(1.0f+__expf(-x)));
  u16 uh = f2bf(s);
  u16 ul = f2bf(s - bf2f(uh));
  spk = (u32)uh | ((u32)ul<<16);
  bpk = basis_pk(x);
}

// ---------------- destination-major weight prep, two formats ----------------
struct PrepArgs {
  const float* bw[7]; const float* sw[7]; const float* sc[7];
  u16* w[7];
  int cin[7]; int coutr[7]; int ntsh[7]; int fmt[7];
  u32 elems[7];
};

__global__ __launch_bounds__(256) void prep_kernel(PrepArgs pa)
{
  u32 idx = blockIdx.x*256 + threadIdx.x;
  int L = 0;
  u32 off = idx;
  while (L < 6 && off >= pa.elems[L]) { off -= pa.elems[L]; ++L; }
  int j    = off & 7;
  int lane = (off>>3) & 63;
  u32 tl   = off >> 9;
  int ntsh = pa.ntsh[L];
  u32 kstep = tl >> ntsh;
  int ntile = (int)(tl & ((1u<<ntsh)-1u));
  int o    = ntile*16 + (lane&15);
  int kpos = (lane>>4)*8 + j;
  int i = 0, g = 0; bool sil;
  if (pa.fmt[L] == 0){
    u32 c = kstep/9u; int r = (int)(kstep - c*9u);
    if (r == 0){ i = (int)c*32 + kpos; sil = true; }
    else { int kl=(r-1)*32+kpos; i=(int)c*32+(kl>>3); g=kl&7; sil = false; }
  } else {
    u32 c = kstep/5u; int r = (int)(kstep - c*5u);
    if (r == 0){ i = (int)c*16 + (kpos>>1); sil = true; }
    else { int kl=(r-1)*32+kpos; i=(int)c*16+(kl>>3); g=kl&7; sil = false; }
  }
  float v = 0.f;
  if (o < pa.coutr[L]) {
    size_t e = (size_t)o*pa.cin[L] + i;
    v = sil ? pa.bw[L][e] : pa.sw[L][e*8+g]*pa.sc[L][e]*0.16666666666666666f;
  }
  pa.w[L][off] = f2bf(v);
}

// ---------------- fused expand + MFMA layer (r10 + vectorized loadX/sil-write) ----
// Expand task remap: thread owns ONE row x 4 CONSECUTIVE features ->
// loadX = 1 dwordx4 (was 4 scalar loads), sil store = 1 ds_write_b64 (was 4 u16).
// Same coalescing (8 rows x 128B segments/wave), same LDS layout.
template<int CIN,int COUT,int GR,int GC,int IN_MODE,int OUT_MODE>
__global__ __launch_bounds__(512,4) void kan_layer(const void* __restrict__ hin_,
    const u16* __restrict__ W, void* __restrict__ hout_)
{
  constexpr int ROWS = 64;
  constexpr int NCH = CIN/32;
  constexpr int TOTK = NCH*9;
  constexpr int NTILES = COUT/16;
  constexpr int MT  = ROWS/(GR*16);
  constexpr int NTL = NTILES/GC;
  static_assert(GR*GC == 8, "wave grid must use all 8 waves");
  static_assert(MT*GR*16 == ROWS, "row coverage");
  static_assert(NTL*GC == NTILES, "col coverage");
  constexpr int SROW=20, BROW=132, BOFF=ROWS*SROW;
  constexpr int CHUNK = BOFF + ROWS*BROW;        // 9728 dw = 38912 B
  constexpr int WSTEP = NTILES*512;              // u16 elems per kstep
  __shared__ __align__(16) u32 buf[2][CHUNK];    // 77824 B -> 2 blocks/CU

  const int b0 = blockIdx.x*ROWS;
  const int tid = threadIdx.x;
  const int wave = tid>>6, lane = tid&63, m = lane&15, quad = lane>>4;
  const int rg = wave / GC, cg = wave % GC;
  const int rbase = rg*(MT*16);
  const int xrow = tid>>3, xfq = (tid&7)*4;      // expand task: row, 4 consecutive f

  const u16*   __restrict__ hb = (const u16*)hin_;
  const float* __restrict__ hf = (const float*)hin_;

  f32x4 acc[MT][NTL];
#pragma unroll
  for (int a=0;a<MT;++a)
#pragma unroll
    for (int n=0;n<NTL;++n) acc[a][n]=(f32x4){0.f,0.f,0.f,0.f};

  // moving prefetch pointer: always points at the next kstep to load
  const u16* wq = W + ((size_t)(cg*NTL)*64 + lane)*8;
  bf16x8 bbuf[3][NTL];
  auto loadB = [&](int kstep, bf16x8* dst){
    if (kstep < TOTK){
#pragma unroll
      for (int nt=0; nt<NTL; ++nt)
        dst[nt] = *(const bf16x8*)(wq + nt*512);
    }
    wq += WSTEP;
  };
  loadB(0, bbuf[0]); loadB(1, bbuf[1]);

  f32x4 xb[2];
  auto loadX = [&](int kc, f32x4* dst){
    int gi = (b0+xrow)*CIN + kc*32 + xfq;
    if (IN_MODE==0){
      *dst = *(const f32x4*)&hf[gi];
    } else {
      ushort4 v = *(const ushort4*)&hb[gi];
      f32x4 r; r[0]=bf2f(v.x); r[1]=bf2f(v.y); r[2]=bf2f(v.z); r[3]=bf2f(v.w);
      *dst = r;
    }
  };
  auto expandChunk = [&](const f32x4 xc, u32* dstb){
    ushort4 spack;
#pragma unroll
    for (int t=0;t<4;++t){
      u16 sil; uint4 bpk;
      expand9(xc[t], sil, bpk);
      ((u16*)&spack)[t] = sil;
      *(uint4*)&dstb[BOFF + xrow*BROW + (xfq+t)*4] = bpk;
    }
    *(ushort4*)((u16*)dstb + xrow*(SROW*2) + xfq) = spack;   // 8B-aligned b64 write
  };

  loadX(0, &xb[0]);
  expandChunk(xb[0], buf[0]);
  if (NCH > 1) loadX(1, &xb[1]);
  __syncthreads();

  for (int kc=0; kc<NCH; ++kc){
    u32* cur = buf[kc&1];
    u32* nxt = buf[(kc+1)&1];
    if (kc+1 < NCH) expandChunk(xb[(kc+1)&1], nxt);
    if (kc+2 < NCH) loadX(kc+2, &xb[kc&1]);
#pragma unroll
    for (int ks=0; ks<9; ++ks){
      loadB(kc*9+ks+2, bbuf[(ks+2)%3]);          // compile-time slot (ks unrolled, 9%3==0)
      bf16x8 af[MT];
#pragma unroll
      for (int mt=0; mt<MT; ++mt){
        int row = rbase + mt*16 + m;
        af[mt] = (ks==0)
          ? *(const bf16x8*)&cur[row*SROW + quad*4]
          : *(const bf16x8*)&cur[BOFF + row*BROW + (ks-1)*16 + quad*4];
      }
#pragma unroll
      for (int nt=0; nt<NTL; ++nt)
#pragma unroll
        for (int mt=0; mt<MT; ++mt)
          acc[mt][nt] = __builtin_amdgcn_mfma_f32_16x16x32_bf16(af[mt], bbuf[ks%3][nt], acc[mt][nt],0,0,0);
    }
    __syncthreads();
  }

#pragma unroll
  for (int mt=0; mt<MT; ++mt)
#pragma unroll
    for (int nt=0; nt<NTL; ++nt)
#pragma unroll
      for (int r=0; r<4; ++r){
        size_t off = (size_t)(b0 + rbase + mt*16 + quad*4 + r)*COUT + (cg*NTL+nt)*16 + m;
        if constexpr (OUT_MODE==0) ((float*)hout_)[off] = acc[mt][nt][r];
        else                       ((u16*)hout_)[off]   = f2bf(acc[mt][nt][r]);
      }
}

// ---------------- fused L2 + tail: h1 -> h2(LDS) -> {L3,L5} -> {L4->adv ; L6->val} ----
// Verbatim r10 (verified 54.2 us): phase K modular slots + ptr-increment; tail
// phases compact runtime-kc loops with 2-mov weight rotation; serial B1/B2.
template<int IN_MODE>
__global__ __launch_bounds__(512,4) void tail2_kernel(const void* __restrict__ h1_,
  const u16* __restrict__ W2, const u16* __restrict__ W3, const u16* __restrict__ W4,
  const u16* __restrict__ W5, const u16* __restrict__ W6,
  float* __restrict__ out_adv, float* __restrict__ out_val)
{
  __shared__ __align__(16) u32 smem[19456];
  float* hH = (float*)smem;               // [64][65]
  float* hA = (float*)(smem + 4160);      // [64][65]
  float* hV = (float*)(smem + 8320);      // [64][65]
  u32*  Aex = smem + 12480;               // 64*20 + 64*68 = 5632 dw

  const int b0 = blockIdx.x*64;
  const int tid = threadIdx.x;
  const int wave = tid>>6, lane = tid&63, m = lane&15, quad = lane>>4;
  const int rg = wave>>2, cg = wave&3;

  const u16*   __restrict__ hb = (const u16*)h1_;
  const float* __restrict__ hf = (const float*)h1_;

  // ======== phase K: L2 ========
  {
    constexpr int CIN=256, NCH=8, TOTK=72, NTILES=4;
    constexpr int SROW=20, BROW=132, BOFF=64*SROW, CHUNK=BOFF+64*BROW; // 9728 dw
    f32x4 acc[2];
    acc[0]=(f32x4){0,0,0,0}; acc[1]=(f32x4){0,0,0,0};
    const u16* wq = W2 + ((size_t)cg*64 + lane)*8;
    bf16x8 bb[3];
    auto loadB = [&](int kstep, bf16x8* dst){
      if (kstep < TOTK) *dst = *(const bf16x8*)wq;
      wq += NTILES*512;
    };
    loadB(0,&bb[0]); loadB(1,&bb[1]);
    float xb[2][4];
    auto loadX = [&](int kc, float* dst){
#pragma unroll
      for (int t=0;t<4;++t){
        int task=t*512+tid, row=task>>5, f=task&31;
        int gi=(b0+row)*CIN + kc*32 + f;
        dst[t] = (IN_MODE==0)? hf[gi] : bf2f(hb[gi]);
      }
    };
    auto expandChunk = [&](const float* xc, u32* dstb){
#pragma unroll
      for (int t=0;t<4;++t){
        int task=t*512+tid, row=task>>5, f=task&31;
        u16 sil; uint4 bpk;
        expand9(xc[t], sil, bpk);
        ((u16*)dstb)[row*(SROW*2)+f] = sil;
        *(uint4*)&dstb[BOFF + row*BROW + f*4] = bpk;
      }
    };
    loadX(0, xb[0]);
    expandChunk(xb[0], smem);
    loadX(1, xb[1]);
    __syncthreads();
    for (int kc=0; kc<NCH; ++kc){
      u32* cur = smem + (kc&1)*CHUNK;
      u32* nxt = smem + ((kc+1)&1)*CHUNK;
      if (kc+1 < NCH) expandChunk(xb[(kc+1)&1], nxt);
      if (kc+2 < NCH) loadX(kc+2, xb[kc&1]);
#pragma unroll
      for (int ks=0; ks<9; ++ks){
        loadB(kc*9+ks+2, &bb[(ks+2)%3]);
        bf16x8 af[2];
#pragma unroll
        for (int mt=0; mt<2; ++mt){
          int row = rg*32 + mt*16 + m;
          af[mt] = (ks==0)
            ? *(const bf16x8*)&cur[row*SROW + quad*4]
            : *(const bf16x8*)&cur[BOFF + row*BROW + (ks-1)*16 + quad*4];
        }
#pragma unroll
        for (int mt=0; mt<2; ++mt)
          acc[mt] = __builtin_amdgcn_mfma_f32_16x16x32_bf16(af[mt], bb[ks%3], acc[mt],0,0,0);
      }
      __syncthreads();
    }
    // h2 tile -> LDS overlay (safe: after final barrier, staging is dead)
#pragma unroll
    for (int mt=0; mt<2; ++mt)
#pragma unroll
      for (int r=0;r<4;++r)
        hH[(rg*32 + mt*16 + quad*4 + r)*65 + cg*16 + m] = acc[mt][r];
  }
  __syncthreads();

  // ======== tail (compact r8 structure), input from hH ========
  constexpr int SROW=20, BROW=68, BOFF=64*20;

  // ---- phase A: expand h2 once, accumulate L3 & L5 ----
  f32x4 a3[2], a5[2];
#pragma unroll
  for (int mt=0;mt<2;++mt){ a3[mt]=(f32x4){0,0,0,0}; a5[mt]=(f32x4){0,0,0,0}; }

  const u16* w3q = W3 + ((size_t)cg*64 + lane)*8;
  const u16* w5q = W5 + ((size_t)cg*64 + lane)*8;
  bf16x8 w3b[3], w5b[3];
  auto loadB2 = [&](int kstep, int d){
    if (kstep < 20){
      w3b[d] = *(const bf16x8*)w3q;
      w5b[d] = *(const bf16x8*)w5q;
    }
    w3q += 4*512; w5q += 4*512;
  };
  loadB2(0,0); loadB2(1,1);

  for (int kc=0; kc<4; ++kc){
#pragma unroll
    for (int t=0;t<2;++t){
      int task=t*512+tid, row=task>>4, f=task&15;
      u32 spk; uint4 bpk;
      expand10(hH[row*65 + kc*16 + f], spk, bpk);
      Aex[row*SROW + f] = spk;
      *(uint4*)&Aex[BOFF + row*BROW + f*4] = bpk;
    }
    __syncthreads();
#pragma unroll
    for (int ks=0; ks<5; ++ks){
      loadB2(kc*5+ks+2, 2);
      bf16x8 af[2];
#pragma unroll
      for (int mt=0; mt<2; ++mt){
        int row = rg*32 + mt*16 + m;
        af[mt] = (ks==0)
          ? *(const bf16x8*)&Aex[row*SROW + quad*4]
          : *(const bf16x8*)&Aex[BOFF + row*BROW + (ks-1)*16 + quad*4];
      }
#pragma unroll
      for (int mt=0; mt<2; ++mt){
        a3[mt] = __builtin_amdgcn_mfma_f32_16x16x32_bf16(af[mt], w3b[0], a3[mt],0,0,0);
        a5[mt] = __builtin_amdgcn_mfma_f32_16x16x32_bf16(af[mt], w5b[0], a5[mt],0,0,0);
      }
      w3b[0]=w3b[1]; w3b[1]=w3b[2]; w5b[0]=w5b[1]; w5b[1]=w5b[2];
    }
    __syncthreads();
  }
#pragma unroll
  for (int mt=0;mt<2;++mt)
#pragma unroll
    for (int r=0;r<4;++r){
      int row = rg*32 + mt*16 + quad*4 + r;
      hA[row*65 + cg*16 + m] = a3[mt][r];
      hV[row*65 + cg*16 + m] = a5[mt][r];
    }
  __syncthreads();

  // ---- phase B1: hA -> L4 -> advantage ----
  f32x4 a4[2];
#pragma unroll
  for (int mt=0;mt<2;++mt) a4[mt]=(f32x4){0,0,0,0};
  const u16* w4q = W4 + ((size_t)cg*64 + lane)*8;
  bf16x8 w4b[3];
  auto loadB4 = [&](int kstep, int d){
    if (kstep < 20) w4b[d] = *(const bf16x8*)w4q;
    w4q += 4*512;
  };
  loadB4(0,0); loadB4(1,1);
  for (int kc=0; kc<4; ++kc){
#pragma unroll
    for (int t=0;t<2;++t){
      int task=t*512+tid, row=task>>4, f=task&15;
      u32 spk; uint4 bpk;
      expand10(hA[row*65 + kc*16 + f], spk, bpk);
      Aex[row*SROW + f] = spk;
      *(uint4*)&Aex[BOFF + row*BROW + f*4] = bpk;
    }
    __syncthreads();
#pragma unroll
    for (int ks=0; ks<5; ++ks){
      loadB4(kc*5+ks+2, 2);
      bf16x8 af[2];
#pragma unroll
      for (int mt=0; mt<2; ++mt){
        int row = rg*32 + mt*16 + m;
        af[mt] = (ks==0)
          ? *(const bf16x8*)&Aex[row*SROW + quad*4]
          : *(const bf16x8*)&Aex[BOFF + row*BROW + (ks-1)*16 + quad*4];
      }
#pragma unroll
      for (int mt=0; mt<2; ++mt)
        a4[mt] = __builtin_amdgcn_mfma_f32_16x16x32_bf16(af[mt], w4b[0], a4[mt],0,0,0);
      w4b[0]=w4b[1]; w4b[1]=w4b[2];
    }
    __syncthreads();
  }
  {
    int col = cg*16 + m;
    if (col < 18){
#pragma unroll
      for (int mt=0;mt<2;++mt)
#pragma unroll
        for (int r=0;r<4;++r)
          out_adv[(size_t)(b0 + rg*32 + mt*16 + quad*4 + r)*18 + col] = a4[mt][r];
    }
  }

  // ---- phase B2: hV -> L6 -> value ----
  f32x4 a6[2];
#pragma unroll
  for (int mt=0;mt<2;++mt) a6[mt]=(f32x4){0,0,0,0};
  const u16* w6q = W6 + ((size_t)cg*64 + lane)*8;
  bf16x8 w6b[3];
  auto loadB6 = [&](int kstep, int d){
    if (kstep < 20) w6b[d] = *(const bf16x8*)w6q;
    w6q += 4*512;
  };
  loadB6(0,0); loadB6(1,1);
  for (int kc=0; kc<4; ++kc){
#pragma unroll
    for (int t=0;t<2;++t){
      int task=t*512+tid, row=task>>4, f=task&15;
      u32 spk; uint4 bpk;
      expand10(hV[row*65 + kc*16 + f], spk, bpk);
      Aex[row*SROW + f] = spk;
      *(uint4*)&Aex[BOFF + row*BROW + f*4] = bpk;
    }
    __syncthreads();
#pragma unroll
    for (int ks=0; ks<5; ++ks){
      loadB6(kc*5+ks+2, 2);
      bf16x8 af[2];
#pragma unroll
      for (int mt=0; mt<2; ++mt){
        int row = rg*32 + mt*16 + m;
        af[mt] = (ks==0)
          ? *(const bf16x8*)&Aex[row*SROW + quad*4]
          : *(const bf16x8*)&Aex[BOFF + row*BROW + (ks-1)*16 + quad*4];
      }
#pragma unroll
      for (int mt=0; mt<2; ++mt)
        a6[mt] = __builtin_amdgcn_mfma_f32_16x16x32_bf16(af[mt], w6b[0], a6[mt],0,0,0);
      w6b[0]=w6b[1]; w6b[1]=w6b[2];
    }
    __syncthreads();
  }
  if (cg==0 && m==0){
#pragma unroll
    for (int mt=0;mt<2;++mt)
#pragma unroll
      for (int r=0;r<4;++r)
        out_val[b0 + rg*32 + mt*16 + quad*4 + r] = a6[mt][r];
  }
}

extern "C" void kernel_launch(void* const* d_in, const int* in_sizes, int n_in,
                              void* d_out, int out_size, void* d_ws, size_t ws_size,
                              hipStream_t stream)
{
  (void)in_sizes; (void)n_in; (void)out_size;
  char* ws = (char*)d_ws;

  // W layouts: L0 36 ksteps x16 tiles, L1 72x16, L2 72x4, L3-6 20x4
  const size_t wbytes[7] = {589824u, 1179648u, 294912u, 81920u, 81920u, 81920u, 81920u};
  const bool midf32 = ws_size >= 77889536u;

  u16* W[7];
  char *h0, *h1;
  if (midf32) {
    h0 = ws;                       // 32768x256 f32
    h1 = h0 + 33554432u;
    size_t off = 75497472u;
    for (int l=0;l<7;++l){ W[l] = (u16*)(ws+off); off += wbytes[l]; }
  } else {
    h0 = ws;                       // bf16 fallback
    h1 = h0 + 16777216u;
    size_t off = 37748736u;
    for (int l=0;l<7;++l){ W[l] = (u16*)(ws+off); off += wbytes[l]; }
  }

  PrepArgs pa;
  const int cins[7]   = {128,256,256,64,64,64,64};
  const int coutr[7]  = {256,256,64,64,18,64,1};
  const int ntsh[7]   = {4,4,2,2,2,2,2};
  const int fmts[7]   = {0,0,0,1,1,1,1};
  const u32 elems[7]  = {294912u,589824u,147456u,40960u,40960u,40960u,40960u};
  for (int l=0;l<7;++l){
    pa.bw[l] = (const float*)d_in[1+3*l];
    pa.sw[l] = (const float*)d_in[2+3*l];
    pa.sc[l] = (const float*)d_in[3+3*l];
    pa.w[l]  = W[l];
    pa.cin[l]=cins[l]; pa.coutr[l]=coutr[l]; pa.ntsh[l]=ntsh[l]; pa.fmt[l]=fmts[l];
    pa.elems[l]=elems[l];
  }
  prep_kernel<<<4672, 256, 0, stream>>>(pa);

  dim3 g64(NROWS/64), bl(512);
  float* out_adv = (float*)d_out;
  float* out_val = (float*)d_out + (size_t)NROWS*18;
  if (midf32) {
    kan_layer<128,256,1,8,0,0><<<g64,bl,0,stream>>>(d_in[0], W[0], h0);
    kan_layer<256,256,1,8,0,0><<<g64,bl,0,stream>>>(h0, W[1], h1);
    tail2_kernel<0><<<g64,bl,0,stream>>>(h1, W[2], W[3], W[4], W[5], W[6], out_adv, out_val);
  } else {
    kan_layer<128,256,1,8,0,1><<<g64,bl,0,stream>>>(d_in[0], W[0], h0);
    kan_layer<256,256,1,8,1,1><<<g64,bl,0,stream>>>(h0, W[1], h1);
    tail2_kernel<1><<<g64,bl,0,stream>>>(h1, W[2], W[3], W[4], W[5], W[6], out_adv, out_val);
  }
}

// Round 15
// 219.277 us; speedup vs baseline: 1.0330x; 1.0072x over previous
//
#include <hip/hip_runtime.h>

typedef unsigned short u16;
typedef unsigned int   u32;
typedef unsigned long long u64;
typedef __bf16 bf16;
typedef float f32x4  __attribute__((ext_vector_type(4)));
typedef bf16  bf16x8 __attribute__((ext_vector_type(8)));

__device__ __forceinline__ float bf2f(u16 u){ return (float)__builtin_bit_cast(bf16,u); }
__device__ __forceinline__ u16   f2bf(float f){ return __builtin_bit_cast(u16,(bf16)f); }
__device__ __forceinline__ u32   pkbf(float a,float b){ return (u32)f2bf(a)|((u32)f2bf(b)<<16); }

#define NROWS 32768

// ---- basis: 8 bf16 slots, NO c6 (folded into B); d2(u)=d1(1-u), d0=w1^3, d3=u^3 ----
__device__ __forceinline__ uint4 basis_pk(float x)
{
  float tp  = __fmaf_rn(x, 2.5f, 5.5f);
  float tpc = fminf(fmaxf(tp, -1.0f), 12.0f);   // out-of-range -> window miss -> zeros
  float fi  = floorf(tpc);
  float uu  = tpc - fi;
  int   i0  = (int)fi;
  float u2 = uu*uu, u3 = u2*uu, w1 = 1.0f-uu, w2 = w1*w1, w3 = w2*w1;
  float d1 = __fmaf_rn(3.0f, u3, __fmaf_rn(-6.0f, u2, 4.0f));
  float d2 = __fmaf_rn(3.0f, w3, __fmaf_rn(-6.0f, w2, 4.0f));
  u64 dpk = (u64)pkbf(w3, d1) | ((u64)pkbf(d2, u3) << 32);
  int ss = i0*16 - 48;
  u64 A  = dpk << (ss & 63);
  u64 Bv = dpk >> ((64-ss) & 63);
  u64 Cv = dpk << ((ss-64) & 63);
  u64 Dv = dpk >> ((-ss) & 63);
  u64 lo = (ss>=0 && ss<64)   ? A  : ((ss<0 && ss>-64) ? Dv : 0ull);
  u64 hi = (ss>=64 && ss<128) ? Cv : ((ss>0 && ss<64)  ? Bv : 0ull);
  uint4 r; r.x=(u32)lo; r.y=(u32)(lo>>32); r.z=(u32)hi; r.w=(u32)(hi>>32);
  return r;
}

// main-layer expansion: single silu slot + bases
__device__ __forceinline__ void expand9(float x, u16& sil, uint4& bpk)
{
  float s = x * (1.0f/(1.0f+__expf(-x)));
  sil = f2bf(s);
  bpk = basis_pk(x);
}
// tail expansion: silu hi/lo pair + bases
__device__ __forceinline__ void expand10(float x, u32& spk, uint4& bpk)
{
  float s = x * (1.0f/(1.0f+__expf(-x)));
  u16 uh = f2bf(s);
  u16 ul = f2bf(s - bf2f(uh));
  spk = (u32)uh | ((u32)ul<<16);
  bpk = basis_pk(x);
}

// ---------------- destination-major weight prep, two formats ----------------
struct PrepArgs {
  const float* bw[7]; const float* sw[7]; const float* sc[7];
  u16* w[7];
  int cin[7]; int coutr[7]; int ntsh[7]; int fmt[7];
  u32 elems[7];
};

__global__ __launch_bounds__(256) void prep_kernel(PrepArgs pa)
{
  u32 idx = blockIdx.x*256 + threadIdx.x;
  int L = 0;
  u32 off = idx;
  while (L < 6 && off >= pa.elems[L]) { off -= pa.elems[L]; ++L; }
  int j    = off & 7;
  int lane = (off>>3) & 63;
  u32 tl   = off >> 9;
  int ntsh = pa.ntsh[L];
  u32 kstep = tl >> ntsh;
  int ntile = (int)(tl & ((1u<<ntsh)-1u));
  int o    = ntile*16 + (lane&15);
  int kpos = (lane>>4)*8 + j;
  int i = 0, g = 0; bool sil;
  if (pa.fmt[L] == 0){
    u32 c = kstep/9u; int r = (int)(kstep - c*9u);
    if (r == 0){ i = (int)c*32 + kpos; sil = true; }
    else { int kl=(r-1)*32+kpos; i=(int)c*32+(kl>>3); g=kl&7; sil = false; }
  } else {
    u32 c = kstep/5u; int r = (int)(kstep - c*5u);
    if (r == 0){ i = (int)c*16 + (kpos>>1); sil = true; }
    else { int kl=(r-1)*32+kpos; i=(int)c*16+(kl>>3); g=kl&7; sil = false; }
  }
  float v = 0.f;
  if (o < pa.coutr[L]) {
    size_t e = (size_t)o*pa.cin[L] + i;
    v = sil ? pa.bw[L][e] : pa.sw[L][e*8+g]*pa.sc[L][e]*0.16666666666666666f;
  }
  pa.w[L][off] = f2bf(v);
}

// ---------------- fused expand + MFMA layer (r14: vectorized loadX/sil-write) ----
// Expand task remap: thread owns ONE row x 4 CONSECUTIVE features ->
// loadX = 1 dwordx4 (was 4 scalar loads), sil store = 1 ds_write_b64 (was 4 u16).
// Same coalescing (8 rows x 128B segments/wave), same LDS layout.
template<int CIN,int COUT,int GR,int GC,int IN_MODE,int OUT_MODE>
__global__ __launch_bounds__(512,4) void kan_layer(const void* __restrict__ hin_,
    const u16* __restrict__ W, void* __restrict__ hout_)
{
  constexpr int ROWS = 64;
  constexpr int NCH = CIN/32;
  constexpr int TOTK = NCH*9;
  constexpr int NTILES = COUT/16;
  constexpr int MT  = ROWS/(GR*16);
  constexpr int NTL = NTILES/GC;
  static_assert(GR*GC == 8, "wave grid must use all 8 waves");
  static_assert(MT*GR*16 == ROWS, "row coverage");
  static_assert(NTL*GC == NTILES, "col coverage");
  constexpr int SROW=20, BROW=132, BOFF=ROWS*SROW;
  constexpr int CHUNK = BOFF + ROWS*BROW;        // 9728 dw = 38912 B
  constexpr int WSTEP = NTILES*512;              // u16 elems per kstep
  __shared__ __align__(16) u32 buf[2][CHUNK];    // 77824 B -> 2 blocks/CU

  const int b0 = blockIdx.x*ROWS;
  const int tid = threadIdx.x;
  const int wave = tid>>6, lane = tid&63, m = lane&15, quad = lane>>4;
  const int rg = wave / GC, cg = wave % GC;
  const int rbase = rg*(MT*16);
  const int xrow = tid>>3, xfq = (tid&7)*4;      // expand task: row, 4 consecutive f

  const u16*   __restrict__ hb = (const u16*)hin_;
  const float* __restrict__ hf = (const float*)hin_;

  f32x4 acc[MT][NTL];
#pragma unroll
  for (int a=0;a<MT;++a)
#pragma unroll
    for (int n=0;n<NTL;++n) acc[a][n]=(f32x4){0.f,0.f,0.f,0.f};

  // moving prefetch pointer: always points at the next kstep to load
  const u16* wq = W + ((size_t)(cg*NTL)*64 + lane)*8;
  bf16x8 bbuf[3][NTL];
  auto loadB = [&](int kstep, bf16x8* dst){
    if (kstep < TOTK){
#pragma unroll
      for (int nt=0; nt<NTL; ++nt)
        dst[nt] = *(const bf16x8*)(wq + nt*512);
    }
    wq += WSTEP;
  };
  loadB(0, bbuf[0]); loadB(1, bbuf[1]);

  f32x4 xb[2];
  auto loadX = [&](int kc, f32x4* dst){
    int gi = (b0+xrow)*CIN + kc*32 + xfq;
    if (IN_MODE==0){
      *dst = *(const f32x4*)&hf[gi];
    } else {
      ushort4 v = *(const ushort4*)&hb[gi];
      f32x4 r; r[0]=bf2f(v.x); r[1]=bf2f(v.y); r[2]=bf2f(v.z); r[3]=bf2f(v.w);
      *dst = r;
    }
  };
  auto expandChunk = [&](const f32x4 xc, u32* dstb){
    ushort4 spack;
#pragma unroll
    for (int t=0;t<4;++t){
      u16 sil; uint4 bpk;
      expand9(xc[t], sil, bpk);
      ((u16*)&spack)[t] = sil;
      *(uint4*)&dstb[BOFF + xrow*BROW + (xfq+t)*4] = bpk;
    }
    *(ushort4*)((u16*)dstb + xrow*(SROW*2) + xfq) = spack;   // 8B-aligned b64 write
  };

  loadX(0, &xb[0]);
  expandChunk(xb[0], buf[0]);
  if (NCH > 1) loadX(1, &xb[1]);
  __syncthreads();

  for (int kc=0; kc<NCH; ++kc){
    u32* cur = buf[kc&1];
    u32* nxt = buf[(kc+1)&1];
    if (kc+1 < NCH) expandChunk(xb[(kc+1)&1], nxt);
    if (kc+2 < NCH) loadX(kc+2, &xb[kc&1]);
#pragma unroll
    for (int ks=0; ks<9; ++ks){
      loadB(kc*9+ks+2, bbuf[(ks+2)%3]);          // compile-time slot (ks unrolled, 9%3==0)
      bf16x8 af[MT];
#pragma unroll
      for (int mt=0; mt<MT; ++mt){
        int row = rbase + mt*16 + m;
        af[mt] = (ks==0)
          ? *(const bf16x8*)&cur[row*SROW + quad*4]
          : *(const bf16x8*)&cur[BOFF + row*BROW + (ks-1)*16 + quad*4];
      }
#pragma unroll
      for (int nt=0; nt<NTL; ++nt)
#pragma unroll
        for (int mt=0; mt<MT; ++mt)
          acc[mt][nt] = __builtin_amdgcn_mfma_f32_16x16x32_bf16(af[mt], bbuf[ks%3][nt], acc[mt][nt],0,0,0);
    }
    __syncthreads();
  }

#pragma unroll
  for (int mt=0; mt<MT; ++mt)
#pragma unroll
    for (int nt=0; nt<NTL; ++nt)
#pragma unroll
      for (int r=0; r<4; ++r){
        size_t off = (size_t)(b0 + rbase + mt*16 + quad*4 + r)*COUT + (cg*NTL+nt)*16 + m;
        if constexpr (OUT_MODE==0) ((float*)hout_)[off] = acc[mt][nt][r];
        else                       ((u16*)hout_)[off]   = f2bf(acc[mt][nt][r]);
      }
}

// ---------------- fused L2 + tail: h1 -> h2(LDS) -> {L3,L5} -> {L4->adv ; L6->val} ----
// r14 structure; phase K expand now uses the same proven row x 4-consecutive-f
// vectorized remap (1 dwordx4 load + 1 b64 silu store). Tail phases unchanged
// (verified 54.2 us form; hH's 65-dw row stride forbids aligned vector loads).
template<int IN_MODE>
__global__ __launch_bounds__(512,4) void tail2_kernel(const void* __restrict__ h1_,
  const u16* __restrict__ W2, const u16* __restrict__ W3, const u16* __restrict__ W4,
  const u16* __restrict__ W5, const u16* __restrict__ W6,
  float* __restrict__ out_adv, float* __restrict__ out_val)
{
  __shared__ __align__(16) u32 smem[19456];
  float* hH = (float*)smem;               // [64][65]
  float* hA = (float*)(smem + 4160);      // [64][65]
  float* hV = (float*)(smem + 8320);      // [64][65]
  u32*  Aex = smem + 12480;               // 64*20 + 64*68 = 5632 dw

  const int b0 = blockIdx.x*64;
  const int tid = threadIdx.x;
  const int wave = tid>>6, lane = tid&63, m = lane&15, quad = lane>>4;
  const int rg = wave>>2, cg = wave&3;
  const int xrow = tid>>3, xfq = (tid&7)*4;      // phase-K expand task

  const u16*   __restrict__ hb = (const u16*)h1_;
  const float* __restrict__ hf = (const float*)h1_;

  // ======== phase K: L2 ========
  {
    constexpr int CIN=256, NCH=8, TOTK=72, NTILES=4;
    constexpr int SROW=20, BROW=132, BOFF=64*SROW, CHUNK=BOFF+64*BROW; // 9728 dw
    f32x4 acc[2];
    acc[0]=(f32x4){0,0,0,0}; acc[1]=(f32x4){0,0,0,0};
    const u16* wq = W2 + ((size_t)cg*64 + lane)*8;
    bf16x8 bb[3];
    auto loadB = [&](int kstep, bf16x8* dst){
      if (kstep < TOTK) *dst = *(const bf16x8*)wq;
      wq += NTILES*512;
    };
    loadB(0,&bb[0]); loadB(1,&bb[1]);
    f32x4 xb[2];
    auto loadX = [&](int kc, f32x4* dst){
      int gi = (b0+xrow)*CIN + kc*32 + xfq;
      if (IN_MODE==0){
        *dst = *(const f32x4*)&hf[gi];
      } else {
        ushort4 v = *(const ushort4*)&hb[gi];
        f32x4 r; r[0]=bf2f(v.x); r[1]=bf2f(v.y); r[2]=bf2f(v.z); r[3]=bf2f(v.w);
        *dst = r;
      }
    };
    auto expandChunk = [&](const f32x4 xc, u32* dstb){
      ushort4 spack;
#pragma unroll
      for (int t=0;t<4;++t){
        u16 sil; uint4 bpk;
        expand9(xc[t], sil, bpk);
        ((u16*)&spack)[t] = sil;
        *(uint4*)&dstb[BOFF + xrow*BROW + (xfq+t)*4] = bpk;
      }
      *(ushort4*)((u16*)dstb + xrow*(SROW*2) + xfq) = spack; // 8B-aligned b64 write
    };
    loadX(0, &xb[0]);
    expandChunk(xb[0], smem);
    loadX(1, &xb[1]);
    __syncthreads();
    for (int kc=0; kc<NCH; ++kc){
      u32* cur = smem + (kc&1)*CHUNK;
      u32* nxt = smem + ((kc+1)&1)*CHUNK;
      if (kc+1 < NCH) expandChunk(xb[(kc+1)&1], nxt);
      if (kc+2 < NCH) loadX(kc+2, &xb[kc&1]);
#pragma unroll
      for (int ks=0; ks<9; ++ks){
        loadB(kc*9+ks+2, &bb[(ks+2)%3]);
        bf16x8 af[2];
#pragma unroll
        for (int mt=0; mt<2; ++mt){
          int row = rg*32 + mt*16 + m;
          af[mt] = (ks==0)
            ? *(const bf16x8*)&cur[row*SROW + quad*4]
            : *(const bf16x8*)&cur[BOFF + row*BROW + (ks-1)*16 + quad*4];
        }
#pragma unroll
        for (int mt=0; mt<2; ++mt)
          acc[mt] = __builtin_amdgcn_mfma_f32_16x16x32_bf16(af[mt], bb[ks%3], acc[mt],0,0,0);
      }
      __syncthreads();
    }
    // h2 tile -> LDS overlay (safe: after final barrier, staging is dead)
#pragma unroll
    for (int mt=0; mt<2; ++mt)
#pragma unroll
      for (int r=0;r<4;++r)
        hH[(rg*32 + mt*16 + quad*4 + r)*65 + cg*16 + m] = acc[mt][r];
  }
  __syncthreads();

  // ======== tail (compact r8 structure), input from hH ========
  constexpr int SROW=20, BROW=68, BOFF=64*20;

  // ---- phase A: expand h2 once, accumulate L3 & L5 ----
  f32x4 a3[2], a5[2];
#pragma unroll
  for (int mt=0;mt<2;++mt){ a3[mt]=(f32x4){0,0,0,0}; a5[mt]=(f32x4){0,0,0,0}; }

  const u16* w3q = W3 + ((size_t)cg*64 + lane)*8;
  const u16* w5q = W5 + ((size_t)cg*64 + lane)*8;
  bf16x8 w3b[3], w5b[3];
  auto loadB2 = [&](int kstep, int d){
    if (kstep < 20){
      w3b[d] = *(const bf16x8*)w3q;
      w5b[d] = *(const bf16x8*)w5q;
    }
    w3q += 4*512; w5q += 4*512;
  };
  loadB2(0,0); loadB2(1,1);

  for (int kc=0; kc<4; ++kc){
#pragma unroll
    for (int t=0;t<2;++t){
      int task=t*512+tid, row=task>>4, f=task&15;
      u32 spk; uint4 bpk;
      expand10(hH[row*65 + kc*16 + f], spk, bpk);
      Aex[row*SROW + f] = spk;
      *(uint4*)&Aex[BOFF + row*BROW + f*4] = bpk;
    }
    __syncthreads();
#pragma unroll
    for (int ks=0; ks<5; ++ks){
      loadB2(kc*5+ks+2, 2);
      bf16x8 af[2];
#pragma unroll
      for (int mt=0; mt<2; ++mt){
        int row = rg*32 + mt*16 + m;
        af[mt] = (ks==0)
          ? *(const bf16x8*)&Aex[row*SROW + quad*4]
          : *(const bf16x8*)&Aex[BOFF + row*BROW + (ks-1)*16 + quad*4];
      }
#pragma unroll
      for (int mt=0; mt<2; ++mt){
        a3[mt] = __builtin_amdgcn_mfma_f32_16x16x32_bf16(af[mt], w3b[0], a3[mt],0,0,0);
        a5[mt] = __builtin_amdgcn_mfma_f32_16x16x32_bf16(af[mt], w5b[0], a5[mt],0,0,0);
      }
      w3b[0]=w3b[1]; w3b[1]=w3b[2]; w5b[0]=w5b[1]; w5b[1]=w5b[2];
    }
    __syncthreads();
  }
#pragma unroll
  for (int mt=0;mt<2;++mt)
#pragma unroll
    for (int r=0;r<4;++r){
      int row = rg*32 + mt*16 + quad*4 + r;
      hA[row*65 + cg*16 + m] = a3[mt][r];
      hV[row*65 + cg*16 + m] = a5[mt][r];
    }
  __syncthreads();

  // ---- phase B1: hA -> L4 -> advantage ----
  f32x4 a4[2];
#pragma unroll
  for (int mt=0;mt<2;++mt) a4[mt]=(f32x4){0,0,0,0};
  const u16* w4q = W4 + ((size_t)cg*64 + lane)*8;
  bf16x8 w4b[3];
  auto loadB4 = [&](int kstep, int d){
    if (kstep < 20) w4b[d] = *(const bf16x8*)w4q;
    w4q += 4*512;
  };
  loadB4(0,0); loadB4(1,1);
  for (int kc=0; kc<4; ++kc){
#pragma unroll
    for (int t=0;t<2;++t){
      int task=t*512+tid, row=task>>4, f=task&15;
      u32 spk; uint4 bpk;
      expand10(hA[row*65 + kc*16 + f], spk, bpk);
      Aex[row*SROW + f] = spk;
      *(uint4*)&Aex[BOFF + row*BROW + f*4] = bpk;
    }
    __syncthreads();
#pragma unroll
    for (int ks=0; ks<5; ++ks){
      loadB4(kc*5+ks+2, 2);
      bf16x8 af[2];
#pragma unroll
      for (int mt=0; mt<2; ++mt){
        int row = rg*32 + mt*16 + m;
        af[mt] = (ks==0)
          ? *(const bf16x8*)&Aex[row*SROW + quad*4]
          : *(const bf16x8*)&Aex[BOFF + row*BROW + (ks-1)*16 + quad*4];
      }
#pragma unroll
      for (int mt=0; mt<2; ++mt)
        a4[mt] = __builtin_amdgcn_mfma_f32_16x16x32_bf16(af[mt], w4b[0], a4[mt],0,0,0);
      w4b[0]=w4b[1]; w4b[1]=w4b[2];
    }
    __syncthreads();
  }
  {
    int col = cg*16 + m;
    if (col < 18){
#pragma unroll
      for (int mt=0;mt<2;++mt)
#pragma unroll
        for (int r=0;r<4;++r)
          out_adv[(size_t)(b0 + rg*32 + mt*16 + quad*4 + r)*18 + col] = a4[mt][r];
    }
  }

  // ---- phase B2: hV -> L6 -> value ----
  f32x4 a6[2];
#pragma unroll
  for (int mt=0;mt<2;++mt) a6[mt]=(f32x4){0,0,0,0};
  const u16* w6q = W6 + ((size_t)cg*64 + lane)*8;
  bf16x8 w6b[3];
  auto loadB6 = [&](int kstep, int d){
    if (kstep < 20) w6b[d] = *(const bf16x8*)w6q;
    w6q += 4*512;
  };
  loadB6(0,0); loadB6(1,1);
  for (int kc=0; kc<4; ++kc){
#pragma unroll
    for (int t=0;t<2;++t){
      int task=t*512+tid, row=task>>4, f=task&15;
      u32 spk; uint4 bpk;
      expand10(hV[row*65 + kc*16 + f], spk, bpk);
      Aex[row*SROW + f] = spk;
      *(uint4*)&Aex[BOFF + row*BROW + f*4] = bpk;
    }
    __syncthreads();
#pragma unroll
    for (int ks=0; ks<5; ++ks){
      loadB6(kc*5+ks+2, 2);
      bf16x8 af[2];
#pragma unroll
      for (int mt=0; mt<2; ++mt){
        int row = rg*32 + mt*16 + m;
        af[mt] = (ks==0)
          ? *(const bf16x8*)&Aex[row*SROW + quad*4]
          : *(const bf16x8*)&Aex[BOFF + row*BROW + (ks-1)*16 + quad*4];
      }
#pragma unroll
      for (int mt=0; mt<2; ++mt)
        a6[mt] = __builtin_amdgcn_mfma_f32_16x16x32_bf16(af[mt], w6b[0], a6[mt],0,0,0);
      w6b[0]=w6b[1]; w6b[1]=w6b[2];
    }
    __syncthreads();
  }
  if (cg==0 && m==0){
#pragma unroll
    for (int mt=0;mt<2;++mt)
#pragma unroll
      for (int r=0;r<4;++r)
        out_val[b0 + rg*32 + mt*16 + quad*4 + r] = a6[mt][r];
  }
}

extern "C" void kernel_launch(void* const* d_in, const int* in_sizes, int n_in,
                              void* d_out, int out_size, void* d_ws, size_t ws_size,
                              hipStream_t stream)
{
  (void)in_sizes; (void)n_in; (void)out_size;
  char* ws = (char*)d_ws;

  // W layouts: L0 36 ksteps x16 tiles, L1 72x16, L2 72x4, L3-6 20x4
  const size_t wbytes[7] = {589824u, 1179648u, 294912u, 81920u, 81920u, 81920u, 81920u};
  const bool midf32 = ws_size >= 77889536u;

  u16* W[7];
  char *h0, *h1;
  if (midf32) {
    h0 = ws;                       // 32768x256 f32
    h1 = h0 + 33554432u;
    size_t off = 75497472u;
    for (int l=0;l<7;++l){ W[l] = (u16*)(ws+off); off += wbytes[l]; }
  } else {
    h0 = ws;                       // bf16 fallback
    h1 = h0 + 16777216u;
    size_t off = 37748736u;
    for (int l=0;l<7;++l){ W[l] = (u16*)(ws+off); off += wbytes[l]; }
  }

  PrepArgs pa;
  const int cins[7]   = {128,256,256,64,64,64,64};
  const int coutr[7]  = {256,256,64,64,18,64,1};
  const int ntsh[7]   = {4,4,2,2,2,2,2};
  const int fmts[7]   = {0,0,0,1,1,1,1};
  const u32 elems[7]  = {294912u,589824u,147456u,40960u,40960u,40960u,40960u};
  for (int l=0;l<7;++l){
    pa.bw[l] = (const float*)d_in[1+3*l];
    pa.sw[l] = (const float*)d_in[2+3*l];
    pa.sc[l] = (const float*)d_in[3+3*l];
    pa.w[l]  = W[l];
    pa.cin[l]=cins[l]; pa.coutr[l]=coutr[l]; pa.ntsh[l]=ntsh[l]; pa.fmt[l]=fmts[l];
    pa.elems[l]=elems[l];
  }
  prep_kernel<<<4672, 256, 0, stream>>>(pa);

  dim3 g64(NROWS/64), bl(512);
  float* out_adv = (float*)d_out;
  float* out_val = (float*)d_out + (size_t)NROWS*18;
  if (midf32) {
    kan_layer<128,256,1,8,0,0><<<g64,bl,0,stream>>>(d_in[0], W[0], h0);
    kan_layer<256,256,1,8,0,0><<<g64,bl,0,stream>>>(h0, W[1], h1);
    tail2_kernel<0><<<g64,bl,0,stream>>>(h1, W[2], W[3], W[4], W[5], W[6], out_adv, out_val);
  } else {
    kan_layer<128,256,1,8,0,1><<<g64,bl,0,stream>>>(d_in[0], W[0], h0);
    kan_layer<256,256,1,8,1,1><<<g64,bl,0,stream>>>(h0, W[1], h1);
    tail2_kernel<1><<<g64,bl,0,stream>>>(h1, W[2], W[3], W[4], W[5], W[6], out_adv, out_val);
  }
}